// Round 2
// baseline (4578.490 us; speedup 1.0000x reference)
//
#include <hip/hip_runtime.h>
#include <hip/hip_fp16.h>

#define NN 20000
#define NE 300000
#define NT 500000
#define HD 128
#define NRR 6
#define NSNRD 42
#define NBB 8

__device__ __forceinline__ float silu_f(float v){ return v / (1.f + __expf(-v)); }

// ---- transpose W_bil [i][jb][l] -> WbT [jb][l][i] (tiny, once per call) ----
__global__ void k_wbilT(const float* __restrict__ Wb, float* __restrict__ WbT){
  int idx = blockIdx.x*256 + threadIdx.x;     // 8*128*128 = 131072 total
  int i = idx & 127, l = (idx>>7) & 127, jb = idx>>14;
  WbT[idx] = Wb[i*1024 + jb*128 + l];
}

// ---- output-block gate + scatter: g[i[e]] += (rbf@lrbf)*x[e]  (block0 path) ----
__global__ void k_gate_scatter(const float* __restrict__ x, const float* __restrict__ rbf,
                               const int* __restrict__ nid, const float* __restrict__ lrbf,
                               float* __restrict__ g){
  __shared__ float ls[NRR*HD];
  int tid = threadIdx.x;
  for(int q=tid;q<NRR*HD;q+=256) ls[q]=lrbf[q];
  __syncthreads();
  int e = blockIdx.x*2 + (tid>>7);
  int h = tid & 127;
  float gate = 0.f;
  #pragma unroll
  for(int q=0;q<NRR;q++) gate += rbf[e*NRR+q]*ls[q*HD+h];
  atomicAdd(&g[nid[e]*HD + h], gate * x[(long)e*HD + h]);
}

// ---- sproj = sbf @ W_sbf  [T,42]@[42,8] ----
__global__ void k_sproj(const float* __restrict__ sbf, const float* __restrict__ Wsbf,
                        float* __restrict__ sp){
  __shared__ float ws[NSNRD*NBB];
  __shared__ float tile[256*NSNRD];
  int tid = threadIdx.x;
  for(int q=tid;q<NSNRD*NBB;q+=256) ws[q]=Wsbf[q];
  long base = (long)blockIdx.x*256*NSNRD;
  long tot = (long)NT*NSNRD;
  for(int q=tid;q<256*NSNRD;q+=256){ long gi=base+q; tile[q] = (gi<tot)? sbf[gi] : 0.f; }
  __syncthreads();
  int t = blockIdx.x*256 + tid;
  if (t < NT){
    float acc[NBB];
    #pragma unroll
    for(int jb=0;jb<NBB;jb++) acc[jb]=0.f;
    #pragma unroll
    for(int q=0;q<NSNRD;q++){
      float v = tile[tid*NSNRD+q];
      #pragma unroll
      for(int jb=0;jb<NBB;jb++) acc[jb] += v*ws[q*NBB+jb];
    }
    #pragma unroll
    for(int jb=0;jb<NBB;jb++) sp[(long)t*NBB+jb]=acc[jb];
  }
}

// ---- x_kj = fp16( silu(x@W_kj + b_kj) * (rbf@W_rbf) )  per-edge ----
__global__ __launch_bounds__(256,2)
void k_edge_kj(const float* __restrict__ x, const float* __restrict__ rbf,
               const float* __restrict__ Wkj, const float* __restrict__ bkj,
               const float* __restrict__ Wrbf, __half* __restrict__ xkj){
  extern __shared__ char sm[];
  float* Ws   = (float*)sm;                       // 65536
  __half* xt  = (__half*)(sm + 65536);            // 8192
  float* wrbf = (float*)(sm + 65536 + 8192);      // 3072
  float* rbft = (float*)(sm + 65536 + 8192 + 3072); // 768
  int tid = threadIdx.x;
  int e0 = blockIdx.x*32;
  for(int q=tid;q<HD*HD;q+=256) Ws[q]=Wkj[q];
  for(int q=tid;q<32*HD;q+=256) xt[q]=__float2half(x[(long)(e0+(q>>7))*HD + (q&127)]);
  for(int q=tid;q<NRR*HD;q+=256) wrbf[q]=Wrbf[q];
  for(int q=tid;q<32*NRR;q+=256) rbft[q]=rbf[(long)e0*NRR + q];
  __syncthreads();
  int c0 = tid & 31, eg = tid>>5;
  float acc[4][4];
  #pragma unroll
  for(int ee=0;ee<4;ee++){
    #pragma unroll
    for(int kk=0;kk<4;kk++) acc[ee][kk]=0.f;
  }
  for(int k=0;k<HD;k++){
    float wv[4], xv[4];
    #pragma unroll
    for(int kk=0;kk<4;kk++) wv[kk]=Ws[k*HD + c0+32*kk];
    #pragma unroll
    for(int ee=0;ee<4;ee++) xv[ee]=__half2float(xt[(eg*4+ee)*HD + k]);
    #pragma unroll
    for(int ee=0;ee<4;ee++){
      #pragma unroll
      for(int kk=0;kk<4;kk++) acc[ee][kk] += xv[ee]*wv[kk];
    }
  }
  #pragma unroll
  for(int ee=0;ee<4;ee++){
    int e = eg*4+ee;
    #pragma unroll
    for(int kk=0;kk<4;kk++){
      int h = c0+32*kk;
      float v = silu_f(acc[ee][kk] + bkj[h]);
      float r = 0.f;
      #pragma unroll
      for(int q=0;q<NRR;q++) r += rbft[e*NRR+q]*wrbf[q*HD+h];
      xkj[(long)(e0+e)*HD + h] = __float2half(v*r);
    }
  }
}

// ---- triplet bilinear + scatter:  agg[ji] += sum_jb sproj[w,jb]*(xg @ WbT[jb]) ----
// 256 thr = 8 groups (tg) x 32 lanes (c0); group handles 4 triplets; lane covers
// output cols {c0, c0+32, c0+64, c0+96}  (32 lanes x 4 = 128 cols exactly).
__global__ __launch_bounds__(256,2)
void k_triplet(const __half* __restrict__ xkj, const float* __restrict__ sproj,
               const int* __restrict__ ikj, const int* __restrict__ iji,
               const float* __restrict__ WbT, float* __restrict__ agg){
  extern __shared__ char sm[];
  float* Wt  = (float*)sm;                 // 128*129*4 = 66048 (pad->conflict-free)
  __half* xg = (__half*)(sm + 66048);      // 32*128*2 = 8192
  float* sp  = (float*)(sm + 74240);       // 32*8*4 = 1024
  int* kjs   = (int*)(sm + 75264);         // 128
  int* jis   = (int*)(sm + 75392);         // 128
  int tid = threadIdx.x;
  int t0 = blockIdx.x*32;
  if (tid < 32){ kjs[tid]=ikj[t0+tid]; jis[tid]=iji[t0+tid]; }
  __syncthreads();
  for(int q=tid;q<32*HD;q+=256){ int t=q>>7, l=q&127; xg[t*HD+l] = xkj[(long)kjs[t]*HD + l]; }
  for(int q=tid;q<32*NBB;q+=256) sp[q] = sproj[(long)t0*NBB + q];
  int c0 = tid&31, tg = tid>>5;
  float outer[4][4];
  #pragma unroll
  for(int tt=0;tt<4;tt++){
    #pragma unroll
    for(int k=0;k<4;k++) outer[tt][k]=0.f;
  }
  for(int jb=0;jb<NBB;jb++){
    __syncthreads();   // prior reads done (also covers xg/sp staging at jb=0)
    for(int q=tid;q<HD*HD;q+=256){ int l=q>>7, i=q&127; Wt[l*129+i] = WbT[jb*16384 + q]; }
    __syncthreads();
    float inner[4][4];
    #pragma unroll
    for(int tt=0;tt<4;tt++){
      #pragma unroll
      for(int k=0;k<4;k++) inner[tt][k]=0.f;
    }
    for(int l=0;l<HD;l++){
      float wv[4], xv[4];
      #pragma unroll
      for(int k=0;k<4;k++) wv[k]=Wt[l*129 + c0 + 32*k];
      #pragma unroll
      for(int tt=0;tt<4;tt++) xv[tt]=__half2float(xg[(tg*4+tt)*HD + l]);
      #pragma unroll
      for(int tt=0;tt<4;tt++){
        #pragma unroll
        for(int k=0;k<4;k++) inner[tt][k] += xv[tt]*wv[k];
      }
    }
    #pragma unroll
    for(int tt=0;tt<4;tt++){
      float sv = sp[(tg*4+tt)*NBB + jb];
      #pragma unroll
      for(int k=0;k<4;k++) outer[tt][k] += sv*inner[tt][k];
    }
  }
  #pragma unroll
  for(int tt=0;tt<4;tt++){
    int ji = jis[tg*4+tt];
    #pragma unroll
    for(int k=0;k<4;k++) atomicAdd(&agg[(long)ji*HD + c0+32*k], outer[tt][k]);
  }
}

// ---- fused: x_ji recompute, +agg, @W_lin, silu, rbf-gate, scatter into g ----
__global__ __launch_bounds__(256,2)
void k_edge_final(const float* __restrict__ x, const float* __restrict__ rbf,
                  const float* __restrict__ agg, const int* __restrict__ nid,
                  const float* __restrict__ Wji, const float* __restrict__ bji,
                  const float* __restrict__ Wlin, const float* __restrict__ blin,
                  const float* __restrict__ lrbf, float* __restrict__ g){
  extern __shared__ char sm[];
  float* Ws   = (float*)sm;                         // 65536 (Wji then Wlin)
  __half* xt  = (__half*)(sm + 65536);              // 8192 (x then xa)
  float* lrb  = (float*)(sm + 65536 + 8192);        // 3072
  float* rbft = (float*)(sm + 65536 + 8192 + 3072); // 768
  int tid = threadIdx.x;
  int e0 = blockIdx.x*32;
  for(int q=tid;q<HD*HD;q+=256) Ws[q]=Wji[q];
  for(int q=tid;q<32*HD;q+=256) xt[q]=__float2half(x[(long)(e0+(q>>7))*HD + (q&127)]);
  for(int q=tid;q<NRR*HD;q+=256) lrb[q]=lrbf[q];
  for(int q=tid;q<32*NRR;q+=256) rbft[q]=rbf[(long)e0*NRR + q];
  __syncthreads();
  int c0 = tid&31, eg = tid>>5;
  float acc[4][4];
  #pragma unroll
  for(int ee=0;ee<4;ee++){
    #pragma unroll
    for(int kk=0;kk<4;kk++) acc[ee][kk]=0.f;
  }
  for(int k=0;k<HD;k++){
    float wv[4], xv[4];
    #pragma unroll
    for(int kk=0;kk<4;kk++) wv[kk]=Ws[k*HD + c0+32*kk];
    #pragma unroll
    for(int ee=0;ee<4;ee++) xv[ee]=__half2float(xt[(eg*4+ee)*HD + k]);
    #pragma unroll
    for(int ee=0;ee<4;ee++){
      #pragma unroll
      for(int kk=0;kk<4;kk++) acc[ee][kk] += xv[ee]*wv[kk];
    }
  }
  float xa[4][4];
  #pragma unroll
  for(int ee=0;ee<4;ee++){
    int e = eg*4+ee;
    #pragma unroll
    for(int kk=0;kk<4;kk++){
      int h = c0+32*kk;
      xa[ee][kk] = silu_f(acc[ee][kk] + bji[h]) + agg[(long)(e0+e)*HD + h];
    }
  }
  __syncthreads();    // all xt reads done
  #pragma unroll
  for(int ee=0;ee<4;ee++){
    #pragma unroll
    for(int kk=0;kk<4;kk++) xt[(eg*4+ee)*HD + c0+32*kk] = __float2half(xa[ee][kk]);
  }
  __syncthreads();
  for(int q=tid;q<HD*HD;q+=256) Ws[q]=Wlin[q];
  __syncthreads();
  float acc2[4][4];
  #pragma unroll
  for(int ee=0;ee<4;ee++){
    #pragma unroll
    for(int kk=0;kk<4;kk++) acc2[ee][kk]=0.f;
  }
  for(int k=0;k<HD;k++){
    float wv[4], xv[4];
    #pragma unroll
    for(int kk=0;kk<4;kk++) wv[kk]=Ws[k*HD + c0+32*kk];
    #pragma unroll
    for(int ee=0;ee<4;ee++) xv[ee]=__half2float(xt[(eg*4+ee)*HD + k]);
    #pragma unroll
    for(int ee=0;ee<4;ee++){
      #pragma unroll
      for(int kk=0;kk<4;kk++) acc2[ee][kk] += xv[ee]*wv[kk];
    }
  }
  #pragma unroll
  for(int ee=0;ee<4;ee++){
    int e = eg*4+ee;
    #pragma unroll
    for(int kk=0;kk<4;kk++){
      int h = c0+32*kk;
      float x2 = silu_f(acc2[ee][kk] + blin[h]);
      float gate = 0.f;
      #pragma unroll
      for(int q=0;q<NRR;q++) gate += rbft[e*NRR+q]*lrb[q*HD+h];
      atomicAdd(&g[(long)nid[e0+e]*HD + h], gate*x2);
    }
  }
}

// ---- one silu-MLP layer on node features: gout = silu(gin@W + b) ----
__global__ __launch_bounds__(256,2)
void k_mlp(const float* __restrict__ gin, const float* __restrict__ W,
           const float* __restrict__ b, float* __restrict__ gout){
  extern __shared__ char sm[];
  float* Ws  = (float*)sm;            // 65536
  __half* xt = (__half*)(sm+65536);   // 8192
  int tid=threadIdx.x; int r0=blockIdx.x*32;
  for(int q=tid;q<HD*HD;q+=256) Ws[q]=W[q];
  for(int q=tid;q<32*HD;q+=256) xt[q]=__float2half(gin[(long)(r0+(q>>7))*HD + (q&127)]);
  __syncthreads();
  int c0=tid&31, eg=tid>>5;
  float acc[4][4];
  #pragma unroll
  for(int ee=0;ee<4;ee++){
    #pragma unroll
    for(int kk=0;kk<4;kk++) acc[ee][kk]=0.f;
  }
  for(int k=0;k<HD;k++){
    float wv[4], xv[4];
    #pragma unroll
    for(int kk=0;kk<4;kk++) wv[kk]=Ws[k*HD + c0+32*kk];
    #pragma unroll
    for(int ee=0;ee<4;ee++) xv[ee]=__half2float(xt[(eg*4+ee)*HD + k]);
    #pragma unroll
    for(int ee=0;ee<4;ee++){
      #pragma unroll
      for(int kk=0;kk<4;kk++) acc[ee][kk] += xv[ee]*wv[kk];
    }
  }
  #pragma unroll
  for(int ee=0;ee<4;ee++){
    #pragma unroll
    for(int kk=0;kk<4;kk++)
      gout[(long)(r0+eg*4+ee)*HD + c0+32*kk] = silu_f(acc[ee][kk] + b[c0+32*kk]);
  }
}

// ---- column-sum over nodes ----
__global__ void k_colsum(const float* __restrict__ gin, float* __restrict__ s){
  int tid=threadIdx.x; int h=tid&127;
  float acc=0.f;
  for(int r = blockIdx.x*2 + (tid>>7); r < NN; r += 512) acc += gin[(long)r*HD + h];
  atomicAdd(&s[h], acc);
}

// ---- final readout: out = s0@OL0 + s1@OL1 (WRITES d_out, no accumulation) ----
__global__ void k_readout(const float* __restrict__ s0, const float* __restrict__ s1,
                          const float* __restrict__ OL, float* __restrict__ out){
  int o = threadIdx.x;
  float acc=0.f;
  for(int h=0;h<HD;h++) acc += s0[h]*OL[h*HD+o] + s1[h]*OL[HD*HD + h*HD+o];
  out[o] = acc;
}

extern "C" void kernel_launch(void* const* d_in, const int* in_sizes, int n_in,
                              void* d_out, int out_size, void* d_ws, size_t ws_size,
                              hipStream_t stream) {
  const float* x     = (const float*)d_in[0];
  const float* rbf   = (const float*)d_in[1];
  const float* sbf   = (const float*)d_in[2];
  const int*   nid   = (const int*)d_in[3];
  const int*   ikj   = (const int*)d_in[4];
  const int*   iji   = (const int*)d_in[5];
  const float* W_rbf = (const float*)d_in[6];
  const float* W_sbf = (const float*)d_in[7];
  const float* W_kj  = (const float*)d_in[8];
  const float* b_kj  = (const float*)d_in[9];
  const float* W_ji  = (const float*)d_in[10];
  const float* b_ji  = (const float*)d_in[11];
  const float* W_bil = (const float*)d_in[12];
  const float* W_lin = (const float*)d_in[13];
  const float* b_lin = (const float*)d_in[14];
  const float* olrbf = (const float*)d_in[15];
  const float* olW   = (const float*)d_in[16];
  const float* olb   = (const float*)d_in[17];
  const float* olin  = (const float*)d_in[18];
  float* out = (float*)d_out;

  // workspace layout
  size_t off = 0;
  auto alloc = [&](size_t bytes)->size_t{ size_t r = off; off = (off + bytes + 255) & ~(size_t)255; return r; };
  size_t o_xkj  = alloc((size_t)NE*HD*2);
  size_t o_sp   = alloc((size_t)NT*NBB*4);
  size_t o_agg  = alloc((size_t)NE*HD*4);
  size_t o_wbT  = alloc((size_t)NBB*HD*HD*4);
  size_t o_g    = alloc((size_t)NN*HD*4);
  size_t o_g2   = alloc((size_t)NN*HD*4);
  size_t o_s0   = alloc(512);
  size_t o_s1   = alloc(512);
  if (off > ws_size) return;   // insufficient workspace: bail (output untouched)
  char* ws = (char*)d_ws;
  __half* xkj = (__half*)(ws + o_xkj);
  float* sp   = (float*)(ws + o_sp);
  float* agg  = (float*)(ws + o_agg);
  float* wbT  = (float*)(ws + o_wbT);
  float* g    = (float*)(ws + o_g);
  float* g2   = (float*)(ws + o_g2);
  float* s0   = (float*)(ws + o_s0);
  float* s1   = (float*)(ws + o_s1);

  const int SH_EDGE = 65536 + 8192 + 3072 + 768;  // 77568
  const int SH_TRIP = 75520;
  const int SH_MLP  = 65536 + 8192;               // 73728
  hipFuncSetAttribute((const void*)k_edge_kj,    hipFuncAttributeMaxDynamicSharedMemorySize, SH_EDGE);
  hipFuncSetAttribute((const void*)k_edge_final, hipFuncAttributeMaxDynamicSharedMemorySize, SH_EDGE);
  hipFuncSetAttribute((const void*)k_triplet,    hipFuncAttributeMaxDynamicSharedMemorySize, SH_TRIP);
  hipFuncSetAttribute((const void*)k_mlp,        hipFuncAttributeMaxDynamicSharedMemorySize, SH_MLP);

  hipMemsetAsync(agg, 0, (size_t)NE*HD*4, stream);
  hipMemsetAsync(g,   0, (size_t)NN*HD*4, stream);
  hipMemsetAsync(s0,  0, 512, stream);
  hipMemsetAsync(s1,  0, 512, stream);

  k_wbilT<<<512,256,0,stream>>>(W_bil, wbT);

  // ---- output block 0 ----
  k_gate_scatter<<<NE/2,256,0,stream>>>(x, rbf, nid, olrbf, g);
  k_mlp<<<NN/32,256,SH_MLP,stream>>>(g,  olW + 0*16384, olb + 0*128, g2);
  k_mlp<<<NN/32,256,SH_MLP,stream>>>(g2, olW + 1*16384, olb + 1*128, g);
  k_mlp<<<NN/32,256,SH_MLP,stream>>>(g,  olW + 2*16384, olb + 2*128, g2);
  k_colsum<<<256,256,0,stream>>>(g2, s0);
  hipMemsetAsync(g, 0, (size_t)NN*HD*4, stream);

  // ---- interaction ----
  k_sproj<<<(NT+255)/256,256,0,stream>>>(sbf, W_sbf, sp);
  k_edge_kj<<<NE/32,256,SH_EDGE,stream>>>(x, rbf, W_kj, b_kj, W_rbf, xkj);
  k_triplet<<<NT/32,256,SH_TRIP,stream>>>(xkj, sp, ikj, iji, wbT, agg);
  k_edge_final<<<NE/32,256,SH_EDGE,stream>>>(x, rbf, agg, nid, W_ji, b_ji, W_lin, b_lin,
                                             olrbf + NRR*HD, g);

  // ---- output block 1 ----
  k_mlp<<<NN/32,256,SH_MLP,stream>>>(g,  olW + 3*16384, olb + 3*128, g2);
  k_mlp<<<NN/32,256,SH_MLP,stream>>>(g2, olW + 4*16384, olb + 4*128, g);
  k_mlp<<<NN/32,256,SH_MLP,stream>>>(g,  olW + 5*16384, olb + 5*128, g2);
  k_colsum<<<256,256,0,stream>>>(g2, s1);

  k_readout<<<1,128,0,stream>>>(s0, s1, olin, out);
}

// Round 3
// 1816.673 us; speedup vs baseline: 2.5203x; 2.5203x over previous
//
#include <hip/hip_runtime.h>
#include <hip/hip_fp16.h>

#define NN 20000
#define NE 300000
#define NT 500000
#define HD 128
#define NRR 6
#define NSNRD 42
#define NBB 8

using f16x8 = __attribute__((ext_vector_type(8))) _Float16;
using f32x4 = __attribute__((ext_vector_type(4))) float;

__device__ __forceinline__ float silu_f(float v){ return v / (1.f + __expf(-v)); }

// ---- W_bil [i][jb][l] -> WB2 fp16 [jb][i][l]  (B^T layout for MFMA frags) ----
__global__ void k_wb2(const float* __restrict__ Wb, __half* __restrict__ WB2){
  int idx = blockIdx.x*256 + threadIdx.x;     // 8*128*128 = 131072 total
  int l = idx & 127, i = (idx>>7) & 127, jb = idx>>14;
  WB2[jb*16384 + i*128 + l] = __float2half(Wb[i*1024 + jb*128 + l]);
}

// ---- output-block gate + scatter: g[i[e]] += (rbf@lrbf)*x[e] ----
__global__ void k_gate_scatter(const float* __restrict__ x, const float* __restrict__ rbf,
                               const int* __restrict__ nid, const float* __restrict__ lrbf,
                               float* __restrict__ g){
  __shared__ float ls[NRR*HD];
  int tid = threadIdx.x;
  for(int q=tid;q<NRR*HD;q+=256) ls[q]=lrbf[q];
  __syncthreads();
  int e = blockIdx.x*2 + (tid>>7);
  int h = tid & 127;
  float gate = 0.f;
  #pragma unroll
  for(int q=0;q<NRR;q++) gate += rbf[e*NRR+q]*ls[q*HD+h];
  atomicAdd(&g[nid[e]*HD + h], gate * x[(long)e*HD + h]);
}

// ---- sproj = sbf @ W_sbf  [T,42]@[42,8] ----
__global__ void k_sproj(const float* __restrict__ sbf, const float* __restrict__ Wsbf,
                        float* __restrict__ sp){
  __shared__ float ws[NSNRD*NBB];
  __shared__ float tile[256*NSNRD];
  int tid = threadIdx.x;
  for(int q=tid;q<NSNRD*NBB;q+=256) ws[q]=Wsbf[q];
  long base = (long)blockIdx.x*256*NSNRD;
  long tot = (long)NT*NSNRD;
  for(int q=tid;q<256*NSNRD;q+=256){ long gi=base+q; tile[q] = (gi<tot)? sbf[gi] : 0.f; }
  __syncthreads();
  int t = blockIdx.x*256 + tid;
  if (t < NT){
    float acc[NBB];
    #pragma unroll
    for(int jb=0;jb<NBB;jb++) acc[jb]=0.f;
    #pragma unroll
    for(int q=0;q<NSNRD;q++){
      float v = tile[tid*NSNRD+q];
      #pragma unroll
      for(int jb=0;jb<NBB;jb++) acc[jb] += v*ws[q*NBB+jb];
    }
    #pragma unroll
    for(int jb=0;jb<NBB;jb++) sp[(long)t*NBB+jb]=acc[jb];
  }
}

// ---- x_kj = fp16( silu(x@W_kj + b_kj) * (rbf@W_rbf) )  per-edge ----
__global__ __launch_bounds__(256,2)
void k_edge_kj(const float* __restrict__ x, const float* __restrict__ rbf,
               const float* __restrict__ Wkj, const float* __restrict__ bkj,
               const float* __restrict__ Wrbf, __half* __restrict__ xkj){
  extern __shared__ char sm[];
  float* Ws   = (float*)sm;
  __half* xt  = (__half*)(sm + 65536);
  float* wrbf = (float*)(sm + 65536 + 8192);
  float* rbft = (float*)(sm + 65536 + 8192 + 3072);
  int tid = threadIdx.x;
  int e0 = blockIdx.x*32;
  for(int q=tid;q<HD*HD;q+=256) Ws[q]=Wkj[q];
  for(int q=tid;q<32*HD;q+=256) xt[q]=__float2half(x[(long)(e0+(q>>7))*HD + (q&127)]);
  for(int q=tid;q<NRR*HD;q+=256) wrbf[q]=Wrbf[q];
  for(int q=tid;q<32*NRR;q+=256) rbft[q]=rbf[(long)e0*NRR + q];
  __syncthreads();
  int c0 = tid & 31, eg = tid>>5;
  float acc[4][4];
  #pragma unroll
  for(int ee=0;ee<4;ee++){
    #pragma unroll
    for(int kk=0;kk<4;kk++) acc[ee][kk]=0.f;
  }
  for(int k=0;k<HD;k++){
    float wv[4], xv[4];
    #pragma unroll
    for(int kk=0;kk<4;kk++) wv[kk]=Ws[k*HD + c0+32*kk];
    #pragma unroll
    for(int ee=0;ee<4;ee++) xv[ee]=__half2float(xt[(eg*4+ee)*HD + k]);
    #pragma unroll
    for(int ee=0;ee<4;ee++){
      #pragma unroll
      for(int kk=0;kk<4;kk++) acc[ee][kk] += xv[ee]*wv[kk];
    }
  }
  #pragma unroll
  for(int ee=0;ee<4;ee++){
    int e = eg*4+ee;
    #pragma unroll
    for(int kk=0;kk<4;kk++){
      int h = c0+32*kk;
      float v = silu_f(acc[ee][kk] + bkj[h]);
      float r = 0.f;
      #pragma unroll
      for(int q=0;q<NRR;q++) r += rbft[e*NRR+q]*wrbf[q*HD+h];
      xkj[(long)(e0+e)*HD + h] = __float2half(v*r);
    }
  }
}

// ---- MFMA triplet bilinear + scatter ----
// t[w,i] = sum_jb sp[w,jb] * (xg[w,:] @ W_bil[:,jb,:]^T)[i]
//        = [T,1024] @ [1024,128] GEMM with A[w, jb*128+l] = sp[w,jb]*xg[w,l]
// Block: 128 rows, 4 waves x (2 row-tiles of 16). jb loop stages Bs=W_bil[.,jb,.]^T.
#define TROWS 128
#define OFF_BS 0
#define OFF_XG 32768
#define OFF_SP 65536
#define OFF_JI 69632
#define OFF_KJ 70144
#define SH_TRIP 70656
__global__ __launch_bounds__(256,2)
void k_triplet_mfma(const __half* __restrict__ xkj, const float* __restrict__ sproj,
                    const int* __restrict__ ikj, const int* __restrict__ iji,
                    const __half* __restrict__ WB2, float* __restrict__ agg){
  extern __shared__ char sm[];
  int tid = threadIdx.x;
  long t0 = (long)blockIdx.x * TROWS;
  int* kjs = (int*)(sm + OFF_KJ);
  int* jis = (int*)(sm + OFF_JI);
  float* spl = (float*)(sm + OFF_SP);
  if (tid < TROWS){
    int ok = (t0 + tid) < NT;
    kjs[tid] = ok ? ikj[t0+tid] : 0;
    jis[tid] = ok ? iji[t0+tid] : -1;
  }
  for(int q=tid;q<TROWS*NBB;q+=256){
    int r = q>>3;
    spl[q] = ((t0+r) < NT) ? sproj[(t0+r)*NBB + (q&7)] : 0.f;
  }
  __syncthreads();   // kjs ready
  // gather xg rows (fp16) with XOR-swizzled 16B chunks
  for(int c=tid;c<TROWS*16;c+=256){
    int w = c>>4, cc = c&15;
    float4 v = *(const float4*)(xkj + (long)kjs[w]*HD + cc*8);
    int dst = (w*256 + cc*16) ^ ((w&7)<<4);
    *(float4*)(sm + OFF_XG + dst) = v;
  }
  __syncthreads();   // xg + sp ready
  int lane = tid & 63, wvid = tid >> 6;
  // per-lane sp for its two row-tiles
  float spreg[2][NBB];
  #pragma unroll
  for(int rt=0;rt<2;rt++){
    int w = wvid*32 + rt*16 + (lane&15);
    #pragma unroll
    for(int jb=0;jb<NBB;jb++) spreg[rt][jb] = spl[w*NBB + jb];
  }
  // unscaled A-fragments: row = lane&15 (+tile), k = (lane>>4)*8 + [0..8)
  f16x8 au[2][4];
  #pragma unroll
  for(int rt=0;rt<2;rt++){
    int w = wvid*32 + rt*16 + (lane&15);
    #pragma unroll
    for(int ks=0;ks<4;ks++){
      int off = (w*256 + ks*64 + (lane>>4)*16) ^ ((w&7)<<4);
      au[rt][ks] = *(const f16x8*)(sm + OFF_XG + off);
    }
  }
  f32x4 acc[2][8];
  #pragma unroll
  for(int rt=0;rt<2;rt++){
    #pragma unroll
    for(int ct=0;ct<8;ct++) acc[rt][ct] = (f32x4){0.f,0.f,0.f,0.f};
  }
  for(int jb=0;jb<NBB;jb++){
    __syncthreads();   // prior Bs reads done
    for(int c=tid;c<2048;c+=256){
      int i = c>>4, lc = c&15;
      float4 v = *(const float4*)(WB2 + jb*16384 + i*128 + lc*8);
      int dst = (i*256 + lc*16) ^ ((i&7)<<4);
      *(float4*)(sm + OFF_BS + dst) = v;
    }
    __syncthreads();
    f16x8 as[2][4];
    #pragma unroll
    for(int rt=0;rt<2;rt++){
      _Float16 s = (_Float16)spreg[rt][jb];
      #pragma unroll
      for(int ks=0;ks<4;ks++){
        #pragma unroll
        for(int j=0;j<8;j++) as[rt][ks][j] = au[rt][ks][j] * s;
      }
    }
    #pragma unroll
    for(int ct=0;ct<8;ct++){
      int i = ct*16 + (lane&15);
      int obase = (i*256 + (lane>>4)*16);
      #pragma unroll
      for(int ks=0;ks<4;ks++){
        f16x8 b = *(const f16x8*)(sm + OFF_BS + ((obase + ks*64) ^ ((i&7)<<4)));
        acc[0][ct] = __builtin_amdgcn_mfma_f32_16x16x32_f16(as[0][ks], b, acc[0][ct], 0,0,0);
        acc[1][ct] = __builtin_amdgcn_mfma_f32_16x16x32_f16(as[1][ks], b, acc[1][ct], 0,0,0);
      }
    }
  }
  // scatter: D row = (lane>>4)*4 + r, col = lane&15
  #pragma unroll
  for(int rt=0;rt<2;rt++){
    #pragma unroll
    for(int r=0;r<4;r++){
      int w = wvid*32 + rt*16 + (lane>>4)*4 + r;
      int ji = jis[w];
      if (ji >= 0){
        #pragma unroll
        for(int ct=0;ct<8;ct++)
          atomicAdd(&agg[(long)ji*HD + ct*16 + (lane&15)], acc[rt][ct][r]);
      }
    }
  }
}

// ---- fused: x_ji recompute, +agg, @W_lin, silu, rbf-gate, scatter into g ----
__global__ __launch_bounds__(256,2)
void k_edge_final(const float* __restrict__ x, const float* __restrict__ rbf,
                  const float* __restrict__ agg, const int* __restrict__ nid,
                  const float* __restrict__ Wji, const float* __restrict__ bji,
                  const float* __restrict__ Wlin, const float* __restrict__ blin,
                  const float* __restrict__ lrbf, float* __restrict__ g){
  extern __shared__ char sm[];
  float* Ws   = (float*)sm;
  __half* xt  = (__half*)(sm + 65536);
  float* lrb  = (float*)(sm + 65536 + 8192);
  float* rbft = (float*)(sm + 65536 + 8192 + 3072);
  int tid = threadIdx.x;
  int e0 = blockIdx.x*32;
  for(int q=tid;q<HD*HD;q+=256) Ws[q]=Wji[q];
  for(int q=tid;q<32*HD;q+=256) xt[q]=__float2half(x[(long)(e0+(q>>7))*HD + (q&127)]);
  for(int q=tid;q<NRR*HD;q+=256) lrb[q]=lrbf[q];
  for(int q=tid;q<32*NRR;q+=256) rbft[q]=rbf[(long)e0*NRR + q];
  __syncthreads();
  int c0 = tid&31, eg = tid>>5;
  float acc[4][4];
  #pragma unroll
  for(int ee=0;ee<4;ee++){
    #pragma unroll
    for(int kk=0;kk<4;kk++) acc[ee][kk]=0.f;
  }
  for(int k=0;k<HD;k++){
    float wv[4], xv[4];
    #pragma unroll
    for(int kk=0;kk<4;kk++) wv[kk]=Ws[k*HD + c0+32*kk];
    #pragma unroll
    for(int ee=0;ee<4;ee++) xv[ee]=__half2float(xt[(eg*4+ee)*HD + k]);
    #pragma unroll
    for(int ee=0;ee<4;ee++){
      #pragma unroll
      for(int kk=0;kk<4;kk++) acc[ee][kk] += xv[ee]*wv[kk];
    }
  }
  float xa[4][4];
  #pragma unroll
  for(int ee=0;ee<4;ee++){
    int e = eg*4+ee;
    #pragma unroll
    for(int kk=0;kk<4;kk++){
      int h = c0+32*kk;
      xa[ee][kk] = silu_f(acc[ee][kk] + bji[h]) + agg[(long)(e0+e)*HD + h];
    }
  }
  __syncthreads();
  #pragma unroll
  for(int ee=0;ee<4;ee++){
    #pragma unroll
    for(int kk=0;kk<4;kk++) xt[(eg*4+ee)*HD + c0+32*kk] = __float2half(xa[ee][kk]);
  }
  __syncthreads();
  for(int q=tid;q<HD*HD;q+=256) Ws[q]=Wlin[q];
  __syncthreads();
  float acc2[4][4];
  #pragma unroll
  for(int ee=0;ee<4;ee++){
    #pragma unroll
    for(int kk=0;kk<4;kk++) acc2[ee][kk]=0.f;
  }
  for(int k=0;k<HD;k++){
    float wv[4], xv[4];
    #pragma unroll
    for(int kk=0;kk<4;kk++) wv[kk]=Ws[k*HD + c0+32*kk];
    #pragma unroll
    for(int ee=0;ee<4;ee++) xv[ee]=__half2float(xt[(eg*4+ee)*HD + k]);
    #pragma unroll
    for(int ee=0;ee<4;ee++){
      #pragma unroll
      for(int kk=0;kk<4;kk++) acc2[ee][kk] += xv[ee]*wv[kk];
    }
  }
  #pragma unroll
  for(int ee=0;ee<4;ee++){
    int e = eg*4+ee;
    #pragma unroll
    for(int kk=0;kk<4;kk++){
      int h = c0+32*kk;
      float x2 = silu_f(acc2[ee][kk] + blin[h]);
      float gate = 0.f;
      #pragma unroll
      for(int q=0;q<NRR;q++) gate += rbft[e*NRR+q]*lrb[q*HD+h];
      atomicAdd(&g[(long)nid[e0+e]*HD + h], gate*x2);
    }
  }
}

// ---- one silu-MLP layer on node features ----
__global__ __launch_bounds__(256,2)
void k_mlp(const float* __restrict__ gin, const float* __restrict__ W,
           const float* __restrict__ b, float* __restrict__ gout){
  extern __shared__ char sm[];
  float* Ws  = (float*)sm;
  __half* xt = (__half*)(sm+65536);
  int tid=threadIdx.x; int r0=blockIdx.x*32;
  for(int q=tid;q<HD*HD;q+=256) Ws[q]=W[q];
  for(int q=tid;q<32*HD;q+=256) xt[q]=__float2half(gin[(long)(r0+(q>>7))*HD + (q&127)]);
  __syncthreads();
  int c0=tid&31, eg=tid>>5;
  float acc[4][4];
  #pragma unroll
  for(int ee=0;ee<4;ee++){
    #pragma unroll
    for(int kk=0;kk<4;kk++) acc[ee][kk]=0.f;
  }
  for(int k=0;k<HD;k++){
    float wv[4], xv[4];
    #pragma unroll
    for(int kk=0;kk<4;kk++) wv[kk]=Ws[k*HD + c0+32*kk];
    #pragma unroll
    for(int ee=0;ee<4;ee++) xv[ee]=__half2float(xt[(eg*4+ee)*HD + k]);
    #pragma unroll
    for(int ee=0;ee<4;ee++){
      #pragma unroll
      for(int kk=0;kk<4;kk++) acc[ee][kk] += xv[ee]*wv[kk];
    }
  }
  #pragma unroll
  for(int ee=0;ee<4;ee++){
    #pragma unroll
    for(int kk=0;kk<4;kk++)
      gout[(long)(r0+eg*4+ee)*HD + c0+32*kk] = silu_f(acc[ee][kk] + b[c0+32*kk]);
  }
}

// ---- column-sum over nodes ----
__global__ void k_colsum(const float* __restrict__ gin, float* __restrict__ s){
  int tid=threadIdx.x; int h=tid&127;
  float acc=0.f;
  for(int r = blockIdx.x*2 + (tid>>7); r < NN; r += 512) acc += gin[(long)r*HD + h];
  atomicAdd(&s[h], acc);
}

// ---- final readout ----
__global__ void k_readout(const float* __restrict__ s0, const float* __restrict__ s1,
                          const float* __restrict__ OL, float* __restrict__ out){
  int o = threadIdx.x;
  float acc=0.f;
  for(int h=0;h<HD;h++) acc += s0[h]*OL[h*HD+o] + s1[h]*OL[HD*HD + h*HD+o];
  out[o] = acc;
}

extern "C" void kernel_launch(void* const* d_in, const int* in_sizes, int n_in,
                              void* d_out, int out_size, void* d_ws, size_t ws_size,
                              hipStream_t stream) {
  const float* x     = (const float*)d_in[0];
  const float* rbf   = (const float*)d_in[1];
  const float* sbf   = (const float*)d_in[2];
  const int*   nid   = (const int*)d_in[3];
  const int*   ikj   = (const int*)d_in[4];
  const int*   iji   = (const int*)d_in[5];
  const float* W_rbf = (const float*)d_in[6];
  const float* W_sbf = (const float*)d_in[7];
  const float* W_kj  = (const float*)d_in[8];
  const float* b_kj  = (const float*)d_in[9];
  const float* W_ji  = (const float*)d_in[10];
  const float* b_ji  = (const float*)d_in[11];
  const float* W_bil = (const float*)d_in[12];
  const float* W_lin = (const float*)d_in[13];
  const float* b_lin = (const float*)d_in[14];
  const float* olrbf = (const float*)d_in[15];
  const float* olW   = (const float*)d_in[16];
  const float* olb   = (const float*)d_in[17];
  const float* olin  = (const float*)d_in[18];
  float* out = (float*)d_out;

  size_t off = 0;
  auto alloc = [&](size_t bytes)->size_t{ size_t r = off; off = (off + bytes + 255) & ~(size_t)255; return r; };
  size_t o_xkj  = alloc((size_t)NE*HD*2);
  size_t o_sp   = alloc((size_t)NT*NBB*4);
  size_t o_agg  = alloc((size_t)NE*HD*4);
  size_t o_wb2  = alloc((size_t)NBB*HD*HD*2);
  size_t o_g    = alloc((size_t)NN*HD*4);
  size_t o_g2   = alloc((size_t)NN*HD*4);
  size_t o_s0   = alloc(512);
  size_t o_s1   = alloc(512);
  if (off > ws_size) return;
  char* ws = (char*)d_ws;
  __half* xkj = (__half*)(ws + o_xkj);
  float* sp   = (float*)(ws + o_sp);
  float* agg  = (float*)(ws + o_agg);
  __half* wb2 = (__half*)(ws + o_wb2);
  float* g    = (float*)(ws + o_g);
  float* g2   = (float*)(ws + o_g2);
  float* s0   = (float*)(ws + o_s0);
  float* s1   = (float*)(ws + o_s1);

  const int SH_EDGE = 65536 + 8192 + 3072 + 768;
  const int SH_MLP  = 65536 + 8192;
  hipFuncSetAttribute((const void*)k_edge_kj,      hipFuncAttributeMaxDynamicSharedMemorySize, SH_EDGE);
  hipFuncSetAttribute((const void*)k_edge_final,   hipFuncAttributeMaxDynamicSharedMemorySize, SH_EDGE);
  hipFuncSetAttribute((const void*)k_triplet_mfma, hipFuncAttributeMaxDynamicSharedMemorySize, SH_TRIP);
  hipFuncSetAttribute((const void*)k_mlp,          hipFuncAttributeMaxDynamicSharedMemorySize, SH_MLP);

  hipMemsetAsync(agg, 0, (size_t)NE*HD*4, stream);
  hipMemsetAsync(g,   0, (size_t)NN*HD*4, stream);
  hipMemsetAsync(s0,  0, 512, stream);
  hipMemsetAsync(s1,  0, 512, stream);

  k_wb2<<<512,256,0,stream>>>(W_bil, wb2);

  // ---- output block 0 ----
  k_gate_scatter<<<NE/2,256,0,stream>>>(x, rbf, nid, olrbf, g);
  k_mlp<<<NN/32,256,SH_MLP,stream>>>(g,  olW + 0*16384, olb + 0*128, g2);
  k_mlp<<<NN/32,256,SH_MLP,stream>>>(g2, olW + 1*16384, olb + 1*128, g);
  k_mlp<<<NN/32,256,SH_MLP,stream>>>(g,  olW + 2*16384, olb + 2*128, g2);
  k_colsum<<<256,256,0,stream>>>(g2, s0);
  hipMemsetAsync(g, 0, (size_t)NN*HD*4, stream);

  // ---- interaction ----
  k_sproj<<<(NT+255)/256,256,0,stream>>>(sbf, W_sbf, sp);
  k_edge_kj<<<NE/32,256,SH_EDGE,stream>>>(x, rbf, W_kj, b_kj, W_rbf, xkj);
  k_triplet_mfma<<<(NT+TROWS-1)/TROWS,256,SH_TRIP,stream>>>(xkj, sp, ikj, iji, wb2, agg);
  k_edge_final<<<NE/32,256,SH_EDGE,stream>>>(x, rbf, agg, nid, W_ji, b_ji, W_lin, b_lin,
                                             olrbf + NRR*HD, g);

  // ---- output block 1 ----
  k_mlp<<<NN/32,256,SH_MLP,stream>>>(g,  olW + 3*16384, olb + 3*128, g2);
  k_mlp<<<NN/32,256,SH_MLP,stream>>>(g2, olW + 4*16384, olb + 4*128, g);
  k_mlp<<<NN/32,256,SH_MLP,stream>>>(g,  olW + 5*16384, olb + 5*128, g2);
  k_colsum<<<256,256,0,stream>>>(g2, s1);

  k_readout<<<1,128,0,stream>>>(s0, s1, olin, out);
}